// Round 1
// baseline (61.489 us; speedup 1.0000x reference)
//
#include <hip/hip_runtime.h>

// Reference collapses: top_k takes ALL K=64 indices (max_chunks == K), and the
// mean over retrieved chunks is permutation-invariant. Output is simply
// mean(knowledge, axis=0) broadcast to [B, S, E]. Query is irrelevant.
//
// Two-phase structure (replaces the old fused kernel, which made all 65536
// threads redundantly re-do the 64-row reduction at 1 wave/SIMD occupancy
// before storing — a latency-bound prologue with no TLP to hide it):
//   Kernel 1 (1 block):  mean(knowledge) -> d_ws (128 float4 = 2 KB), once.
//   Kernel 2 (2048 blk): pure broadcast store at full occupancy — one
//                        L2-broadcast float4 load + one coalesced 16B store
//                        per thread. Structurally a memset; the harness's own
//                        fill kernel shows this shape runs at ~6.4 TB/s.
// Stream order guarantees k1 -> k2 visibility of d_ws. No sync APIs, no
// hipMalloc — graph-capture safe.

#define E_DIM 512
#define K_DIM 64
#define NF4   (E_DIM / 4)        // 128 float4 per knowledge row

// ---------------------------------------------------------------------------
// Kernel 1: 256 threads compute the column mean of knowledge [64][512].
// Thread t handles f4-column (t & 127), half (t >> 7): sums 32 rows each
// (32 independent unrolled loads), pair-reduced through LDS.
// ---------------------------------------------------------------------------
__global__ void __launch_bounds__(256)
knr_mean_kernel(const float4* __restrict__ knowledge4,  // [64 * 128] float4
                float4* __restrict__ mean4) {           // [128] float4 (d_ws)
    __shared__ float4 part[256];
    const int t = threadIdx.x;
    const int c = t & (NF4 - 1);
    const int h = t >> 7;                // 0 or 1 -> rows [0,32) or [32,64)

    float4 s = make_float4(0.f, 0.f, 0.f, 0.f);
#pragma unroll
    for (int k = 0; k < K_DIM / 2; ++k) {
        float4 v = knowledge4[(h * (K_DIM / 2) + k) * NF4 + c];
        s.x += v.x; s.y += v.y; s.z += v.z; s.w += v.w;
    }
    part[t] = s;
    __syncthreads();

    if (t < NF4) {
        const float4 a = part[t];
        const float4 b = part[t + NF4];
        const float inv = 1.0f / K_DIM;
        float4 m;
        m.x = (a.x + b.x) * inv;
        m.y = (a.y + b.y) * inv;
        m.z = (a.z + b.z) * inv;
        m.w = (a.w + b.w) * inv;
        mean4[t] = m;
    }
}

// ---------------------------------------------------------------------------
// Kernel 2: pure broadcast store. 524288 threads, 1 float4 each.
// mean4 is 2 KB — L1/L2-broadcast-resident after first touch per CU.
// ---------------------------------------------------------------------------
__global__ void __launch_bounds__(256)
knr_bcast_kernel(const float4* __restrict__ mean4,
                 float4* __restrict__ out,
                 int total_f4) {
    const int i = blockIdx.x * 256 + threadIdx.x;
    if (i < total_f4) {
        out[i] = mean4[i & (NF4 - 1)];
    }
}

extern "C" void kernel_launch(void* const* d_in, const int* in_sizes, int n_in,
                              void* d_out, int out_size, void* d_ws, size_t ws_size,
                              hipStream_t stream) {
    // d_in[0] = query_embedding [4,1024,512] fp32 (unused — see analysis above)
    // d_in[1] = knowledge [64,512] fp32
    const float4* knowledge4 = (const float4*)d_in[1];
    float4* mean4 = (float4*)d_ws;       // 2 KB scratch
    float4* out = (float4*)d_out;
    const int total_f4 = out_size / 4;   // 524288

    knr_mean_kernel<<<1, 256, 0, stream>>>(knowledge4, mean4);

    const int blocks = (total_f4 + 255) / 256;  // 2048
    knr_bcast_kernel<<<blocks, 256, 0, stream>>>(mean4, out, total_f4);
}